// Round 1
// baseline (141.223 us; speedup 1.0000x reference)
//
#include <hip/hip_runtime.h>

// ---------------------------------------------------------------------------
// KAN conv:  out[b,o,l] = sum_{c,p} silu(t[b,c,l,p])*scale_base[o,c,p]
//                       + sum_{c,p,m} Bspline_m(t[b,c,l,p])*scale_sp[o,c,p]*coef[o,c,p,m]
//                       + bias[o]
// t = 3x3 patches of zero-padded x.  Reformulated as GEMM:
//   A [8192 x 2816] bf16 (features, per-c block of 88 = 9*9 feats + 7 pad)
//   Wb[  64 x 2816] bf16 (folded weights, pads = 0)
//   out = A * Wb^T + bias   via mfma_f32_16x16x32_bf16
// Workspace: A = 46,137,344 B, Wb = 360,448 B  (total ~46.5 MB of d_ws)
// ---------------------------------------------------------------------------

typedef __attribute__((ext_vector_type(8))) short v8s;
typedef __attribute__((ext_vector_type(4))) float v4f;
typedef unsigned short ushort_t;

#define KD        2816           // 32 channels * 88
#define A_ELEMS   (8192u * 2816u)   // ushort elements; 46,137,344 bytes (16B-aligned)

__device__ __forceinline__ unsigned short f2bf(float v) {
  union { float f; unsigned int u; } w; w.f = v;
  unsigned int r = w.u + 0x7FFFu + ((w.u >> 16) & 1u);   // round-to-nearest-even
  return (unsigned short)(r >> 16);
}

// ---------------------------------------------------------------------------
// Kernel 1: out = bias  (524288 threads)  +  build Wb bf16 (180224 threads)
// ---------------------------------------------------------------------------
__global__ __launch_bounds__(256) void kan_prep(const float* __restrict__ coef,
                                                const float* __restrict__ sb,
                                                const float* __restrict__ ssp,
                                                const float* __restrict__ bias,
                                                ushort_t* __restrict__ Wb,
                                                float* __restrict__ out) {
  int tid = blockIdx.x * 256 + threadIdx.x;
  if (tid < 524288) {                       // out[b][o][l] = bias[o]
    out[tid] = bias[(tid >> 10) & 63];
    return;
  }
  int i = tid - 524288;                     // Wb flat index: o*2816 + c*88 + q
  if (i >= 64 * KD) return;
  int o = i / KD;
  int r = i - o * KD;
  int c = r / 88;
  int q = r - c * 88;
  float val = 0.0f;
  if (q < 81) {
    int p = q / 9;
    int j = q - p * 9;
    int sidx = (o * 32 + c) * 9 + p;        // scale_base / scale_sp index
    val = (j == 0) ? sb[sidx] : ssp[sidx] * coef[sidx * 8 + (j - 1)];
  }
  Wb[i] = f2bf(val);
}

// ---------------------------------------------------------------------------
// Kernel 2: features.  One thread per (b,c,oh,ow) = x-flat order (coalesced x
// reads).  Writes 88 bf16 (11 x uint4, 16B-aligned: c*88 elems = c*176 B).
// Closed-form uniform cubic B-spline: for u=(t+2.2)*2.5, i=floor(u), s=u-i,
// nonzero bases j=i-3..i with the 4 standard cubic pieces.  t outside
// [-2.2,2.2) -> all bases 0 (matches Cox-de Boor truncation).  Pad value t=0
// still gets real basis values (padding contributes!).
// ---------------------------------------------------------------------------
__global__ __launch_bounds__(256) void kan_feat(const float* __restrict__ x,
                                                ushort_t* __restrict__ A) {
  int tid = blockIdx.x * 256 + threadIdx.x;   // 262144 = 8*32*32*32
  int ow = tid & 31;
  int oh = (tid >> 5) & 31;
  int c  = (tid >> 10) & 31;
  int b  = tid >> 15;
  const float* xp = x + tid;                  // x[b][c][oh][ow]

  float t[9];
#pragma unroll
  for (int di = 0; di < 3; ++di) {
#pragma unroll
    for (int dj = 0; dj < 3; ++dj) {
      int h = oh + di - 1, w = ow + dj - 1;
      bool ok = (h >= 0) && (h < 32) && (w >= 0) && (w < 32);
      t[di * 3 + dj] = ok ? xp[(di - 1) * 32 + (dj - 1)] : 0.0f;
    }
  }

  union { unsigned short h[88]; uint4 v[11]; } fb;
#pragma unroll
  for (int i = 0; i < 11; ++i) fb.v[i] = make_uint4(0u, 0u, 0u, 0u);

#pragma unroll
  for (int p = 0; p < 9; ++p) {
    float v = t[p];
    fb.h[p * 9] = f2bf(v / (1.0f + __expf(-v)));       // silu
    float u  = (v + 2.2f) * 2.5f;
    float fi = floorf(u);
    int   i  = (int)fi;
    float s  = u - fi;
    float s2 = s * s, s3 = s2 * s;
    float om = 1.0f - s;
    float w0 = om * om * om * (1.0f / 6.0f);                   // j = i-3
    float w1 = (4.0f - 6.0f * s2 + 3.0f * s3) * (1.0f / 6.0f); // j = i-2
    float w2 = (1.0f + 3.0f * s + 3.0f * s2 - 3.0f * s3) * (1.0f / 6.0f); // j = i-1
    float w3 = s3 * (1.0f / 6.0f);                             // j = i
#pragma unroll
    for (int jj = 0; jj < 8; ++jj) {
      int d = jj - i + 3;                    // which of the 4 pieces (0..3), else 0
      float bv = (d == 0) ? w0 : (d == 1) ? w1 : (d == 2) ? w2 : (d == 3) ? w3 : 0.0f;
      fb.h[p * 9 + 1 + jj] = f2bf(bv);
    }
  }

  int l = b * 1024 + oh * 32 + ow;           // pixel row in A
  uint4* dst = (uint4*)(A + (size_t)l * KD + (size_t)c * 88);
#pragma unroll
  for (int i = 0; i < 11; ++i) dst[i] = fb.v[i];
}

// ---------------------------------------------------------------------------
// Kernel 3: GEMM  out[l][o] += A[l][:] . Wb[o][:]
// Block: 256 thr = 4 waves, M-tile 64 (wave = 16 rows), N = 64 (4 n-tiles),
// K-split 4 over blockIdx.y (22 K-steps of 32 each).  No LDS: A-frag is
// 16 rows x 64B contiguous segments streamed from HBM (read exactly once);
// B-frags hit L1/L2 (Wb = 352 KB).  fp32 atomicAdd epilogue onto bias-inited out.
// A-frag: lane holds A[m=lane&15][k=quad*8+j]; B-frag: Wb[o=lane&15][k=quad*8+j];
// D: col(o)=lane&15, row(m)=quad*4+reg.
// ---------------------------------------------------------------------------
__global__ __launch_bounds__(256) void kan_gemm(const ushort_t* __restrict__ A,
                                                const ushort_t* __restrict__ Wb,
                                                float* __restrict__ out) {
  const int lane = threadIdx.x & 63;
  const int wave = threadIdx.x >> 6;
  const int row  = lane & 15;
  const int quad = lane >> 4;
  const int mbase = blockIdx.x * 64 + wave * 16;
  const int kbase = blockIdx.y * 704;        // 22 steps * 32

  const ushort_t* Ap = A  + (size_t)(mbase + row) * KD + quad * 8 + kbase;
  const ushort_t* Bp = Wb + (size_t)row * KD + quad * 8 + kbase;

  v4f acc0 = {0.f, 0.f, 0.f, 0.f};
  v4f acc1 = acc0, acc2 = acc0, acc3 = acc0;

#pragma unroll 2
  for (int s = 0; s < 22; ++s) {
    v8s a  = *(const v8s*)(Ap);
    v8s b0 = *(const v8s*)(Bp);
    v8s b1 = *(const v8s*)(Bp + 16 * KD);
    v8s b2 = *(const v8s*)(Bp + 32 * KD);
    v8s b3 = *(const v8s*)(Bp + 48 * KD);
    acc0 = __builtin_amdgcn_mfma_f32_16x16x32_bf16(a, b0, acc0, 0, 0, 0);
    acc1 = __builtin_amdgcn_mfma_f32_16x16x32_bf16(a, b1, acc1, 0, 0, 0);
    acc2 = __builtin_amdgcn_mfma_f32_16x16x32_bf16(a, b2, acc2, 0, 0, 0);
    acc3 = __builtin_amdgcn_mfma_f32_16x16x32_bf16(a, b3, acc3, 0, 0, 0);
    Ap += 32; Bp += 32;
  }

#pragma unroll
  for (int r = 0; r < 4; ++r) {
    int m = mbase + quad * 4 + r;            // global pixel l
    float* obase = out + (size_t)((m >> 10) * 64) * 1024 + (m & 1023);
    atomicAdd(obase + (size_t)(row)      * 1024, acc0[r]);
    atomicAdd(obase + (size_t)(row + 16) * 1024, acc1[r]);
    atomicAdd(obase + (size_t)(row + 32) * 1024, acc2[r]);
    atomicAdd(obase + (size_t)(row + 48) * 1024, acc3[r]);
  }
}

// ---------------------------------------------------------------------------
extern "C" void kernel_launch(void* const* d_in, const int* in_sizes, int n_in,
                              void* d_out, int out_size, void* d_ws, size_t ws_size,
                              hipStream_t stream) {
  const float* x    = (const float*)d_in[0];
  const float* coef = (const float*)d_in[1];
  const float* sb   = (const float*)d_in[2];
  const float* ssp  = (const float*)d_in[3];
  const float* bias = (const float*)d_in[4];
  float* out = (float*)d_out;

  ushort_t* A  = (ushort_t*)d_ws;            // 46,137,344 B
  ushort_t* Wb = A + A_ELEMS;                // +360,448 B  (needs ws >= ~46.5 MB)

  hipLaunchKernelGGL(kan_prep, dim3(2752), dim3(256), 0, stream,
                     coef, sb, ssp, bias, Wb, out);
  hipLaunchKernelGGL(kan_feat, dim3(1024), dim3(256), 0, stream, x, A);
  hipLaunchKernelGGL(kan_gemm, dim3(128, 4), dim3(256), 0, stream, A, Wb, out);
}

// Round 2
// 85.388 us; speedup vs baseline: 1.6539x; 1.6539x over previous
//
#include <hip/hip_runtime.h>

// ---------------------------------------------------------------------------
// KAN conv reformulated as a 3x3 conv with Cin=288, Cout=64:
//   feature tensor g[b][h][w][j][c], (h,w) padded 34x34, j in 0..8
//     j=0: silu(t), j=1..8: cubic B-spline basis values of t
//     border cells: t=0 (basis(0) != 0 -> must be materialized!)
//   weights Wb[o][pos][j][c] (pos = 3x3 position), bf16, 331,776 B
//   out[b][o][oh][ow] = sum_{pos,j,c} g[b][oh+di][ow+dj][j][c] * Wb[o][pos][j][c] + bias[o]
// via mfma_f32_16x16x32_bf16, no atomics, direct float4 stores.
// Workspace: g = 5,326,848 B, Wb = 331,776 B (~5.7 MB of d_ws).
// ---------------------------------------------------------------------------

typedef __attribute__((ext_vector_type(8))) short v8s;
typedef __attribute__((ext_vector_type(4))) float v4f;
typedef unsigned short ushort_t;

#define G_ELEMS   (8u * 34u * 34u * 288u)   // 2,663,424 bf16
#define WB_ELEMS  (64u * 2592u)             // 165,888 bf16
#define N_FEAT    (8 * 34 * 34 * 32)        // 295,936 feature threads
#define N_TOTAL   (N_FEAT + 64 * 2592)      // + 165,888 Wb threads = 461,824

__device__ __forceinline__ unsigned short f2bf(float v) {
  union { float f; unsigned int u; } w; w.f = v;
  unsigned int r = w.u + 0x7FFFu + ((w.u >> 16) & 1u);   // round-to-nearest-even
  return (unsigned short)(r >> 16);
}

// ---------------------------------------------------------------------------
// Kernel 1: build g (padded feature tensor) and Wb (folded bf16 weights).
//   feature threads: tid = ((b*34 + h)*34 + w)*32 + c   (c fastest -> writes
//   at g_cell + j*32 + c are coalesced 64B segments per j)
// ---------------------------------------------------------------------------
__global__ __launch_bounds__(256) void kan_feat(const float* __restrict__ x,
                                                const float* __restrict__ coef,
                                                const float* __restrict__ sb,
                                                const float* __restrict__ ssp,
                                                ushort_t* __restrict__ g,
                                                ushort_t* __restrict__ Wb) {
  int tid = blockIdx.x * 256 + threadIdx.x;
  if (tid < N_FEAT) {
    int c = tid & 31;
    int cell = tid >> 5;              // (b*34 + h)*34 + w
    int w = cell % 34;
    int hb = cell / 34;
    int h = hb % 34;
    int b = hb / 34;

    bool inb = (h >= 1) && (h <= 32) && (w >= 1) && (w <= 32);
    float t = 0.0f;
    if (inb) t = x[((b * 32 + c) * 32 + (h - 1)) * 32 + (w - 1)];

    // silu
    unsigned short f0 = f2bf(t / (1.0f + __expf(-t)));
    // cubic uniform B-spline on knots -2.2 + 0.4*i (12 knots, 8 bases)
    float u  = (t + 2.2f) * 2.5f;
    float fi = floorf(u);
    int   i  = (int)fi;
    float s  = u - fi;
    float s2 = s * s, s3 = s2 * s;
    float om = 1.0f - s;
    float w0 = om * om * om * (1.0f / 6.0f);                              // j = i-3
    float w1 = (4.0f - 6.0f * s2 + 3.0f * s3) * (1.0f / 6.0f);            // j = i-2
    float w2 = (1.0f + 3.0f * s + 3.0f * s2 - 3.0f * s3) * (1.0f / 6.0f); // j = i-1
    float w3 = s3 * (1.0f / 6.0f);                                        // j = i

    ushort_t* dst = g + (size_t)cell * 288 + c;
    dst[0] = f0;
#pragma unroll
    for (int jj = 0; jj < 8; ++jj) {
      int d = jj - i + 3;
      float bv = (d == 0) ? w0 : (d == 1) ? w1 : (d == 2) ? w2 : (d == 3) ? w3 : 0.0f;
      dst[(jj + 1) * 32] = f2bf(bv);
    }
    return;
  }
  int i2 = tid - N_FEAT;              // Wb flat: o*2592 + pos*288 + j*32 + c
  if (i2 >= (int)WB_ELEMS) return;
  int o = i2 / 2592;
  int r = i2 - o * 2592;
  int pos = r / 288;
  int rj = r - pos * 288;
  int j = rj >> 5;
  int c = rj & 31;
  int sidx = (o * 32 + c) * 9 + pos;
  float val = (j == 0) ? sb[sidx] : ssp[sidx] * coef[sidx * 8 + (j - 1)];
  Wb[i2] = f2bf(val);
}

// ---------------------------------------------------------------------------
// Kernel 2: the conv-GEMM.  256 blocks (one per image row: b*32+oh), 4 waves.
// Wave = M16 x N32: ow_base = (wave&1)*16, nbase = (wave>>1)*32.
// K-loop: 9 patch positions x 9 ksteps of 32 (one kstep = one j, all 32 c).
// A-frag: lane(row=lane&15, quad) reads g[cell(oh+di, ow_base+row+dj)] + kk*32 + quad*8
// B-frag: Wb[(nbase + [0|16] + row)*2592 + pos*288 + kk*32 + quad*8]
// D: col(o)=lane&15, row(pixel)=quad*4+reg -> float4 store, bias fused.
// ---------------------------------------------------------------------------
__global__ __launch_bounds__(256) void kan_conv(const ushort_t* __restrict__ g,
                                                const ushort_t* __restrict__ Wb,
                                                const float* __restrict__ bias,
                                                float* __restrict__ out) {
  const int lane = threadIdx.x & 63;
  const int wave = threadIdx.x >> 6;
  const int row  = lane & 15;
  const int quad = lane >> 4;
  const int mrow = blockIdx.x;            // b*32 + oh
  const int b  = mrow >> 5;
  const int oh = mrow & 31;
  const int ow_base = (wave & 1) * 16;
  const int nbase   = (wave >> 1) * 32;

  const ushort_t* gb  = g + ((size_t)((b * 34 + oh) * 34 + ow_base + row)) * 288 + quad * 8;
  const ushort_t* wb0 = Wb + (size_t)(nbase + row) * 2592 + quad * 8;
  const ushort_t* wb1 = wb0 + 16 * 2592;

  v4f acc0 = {0.f, 0.f, 0.f, 0.f};
  v4f acc1 = acc0;

#pragma unroll
  for (int di = 0; di < 3; ++di) {
#pragma unroll
    for (int dj = 0; dj < 3; ++dj) {
      const ushort_t* ap  = gb + (di * 34 + dj) * 288;
      const ushort_t* bp0 = wb0 + (di * 3 + dj) * 288;
      const ushort_t* bp1 = wb1 + (di * 3 + dj) * 288;
#pragma unroll
      for (int kk = 0; kk < 9; ++kk) {
        v8s a  = *(const v8s*)(ap  + kk * 32);
        v8s b0 = *(const v8s*)(bp0 + kk * 32);
        v8s b1 = *(const v8s*)(bp1 + kk * 32);
        acc0 = __builtin_amdgcn_mfma_f32_16x16x32_bf16(a, b0, acc0, 0, 0, 0);
        acc1 = __builtin_amdgcn_mfma_f32_16x16x32_bf16(a, b1, acc1, 0, 0, 0);
      }
    }
  }

  const int o0 = nbase + row;
  const float bv0 = bias[o0];
  const float bv1 = bias[o0 + 16];
  float* p0 = out + ((size_t)(b * 64 + o0)) * 1024 + oh * 32 + ow_base + quad * 4;
  float* p1 = p0 + 16 * 1024;
  *(float4*)p0 = make_float4(acc0[0] + bv0, acc0[1] + bv0, acc0[2] + bv0, acc0[3] + bv0);
  *(float4*)p1 = make_float4(acc1[0] + bv1, acc1[1] + bv1, acc1[2] + bv1, acc1[3] + bv1);
}

// ---------------------------------------------------------------------------
extern "C" void kernel_launch(void* const* d_in, const int* in_sizes, int n_in,
                              void* d_out, int out_size, void* d_ws, size_t ws_size,
                              hipStream_t stream) {
  const float* x    = (const float*)d_in[0];
  const float* coef = (const float*)d_in[1];
  const float* sb   = (const float*)d_in[2];
  const float* ssp  = (const float*)d_in[3];
  const float* bias = (const float*)d_in[4];
  float* out = (float*)d_out;

  ushort_t* g  = (ushort_t*)d_ws;          // 5,326,848 B
  ushort_t* Wb = g + G_ELEMS;              // +331,776 B

  hipLaunchKernelGGL(kan_feat, dim3((N_TOTAL + 255) / 256), dim3(256), 0, stream,
                     x, coef, sb, ssp, g, Wb);
  hipLaunchKernelGGL(kan_conv, dim3(256), dim3(256), 0, stream, g, Wb, bias, out);
}